// Round 4
// baseline (37.318 us; speedup 1.0000x reference)
//
#include <hip/hip_runtime.h>

// CRF forward (buggy-LSE reference) telescoped into per-token parallel form.
// R4: 2 tokens/thread + base-2 domain (raw v_exp/v_log, single xln2 at end).
// 3 dispatches: prep (et=exp(T), t2=T*log2e) -> main -> reduce.
//
// ws layout: [0] 64f et ; [256B] 64f t2 ; [1024B] partials [2048].

#define L2E 1.44269504088896340736f
#define LN2 0.69314718055994530942f

__global__ void prep_kernel(const float* __restrict__ trans,
                            float* __restrict__ et, float* __restrict__ t2) {
    int i = threadIdx.x;   // 64 threads
    float v = trans[i];
    et[i] = __expf(v);
    t2[i] = v * L2E;
}

// payload-at-argmax per row a over b of h[b] = f2[b] + T2[b,a]; payload v0[b].
__device__ __forceinline__ void compute_va(const float f2[8],
                                           const float* __restrict__ t2,
                                           float va[8]) {
    float v0[8];
    #pragma unroll
    for (int b = 0; b < 8; ++b) v0[b] = f2[b] + t2[b * 8];
    // row 0: keys == payloads -> payload at argmax is the max
    va[0] = fmaxf(fmaxf(fmaxf(fmaxf(v0[0], v0[1]), v0[2]),
                        fmaxf(fmaxf(v0[3], v0[4]), v0[5])),
                  fmaxf(v0[6], v0[7]));
    #pragma unroll
    for (int a = 1; a < 8; ++a) {
        float h[8];
        #pragma unroll
        for (int b = 0; b < 8; ++b) h[b] = f2[b] + t2[b * 8 + a];
        float hm = fmaxf(fmaxf(fmaxf(fmaxf(h[0], h[1]), h[2]),
                               fmaxf(fmaxf(h[3], h[4]), h[5])),
                         fmaxf(h[6], h[7]));
        float vb = v0[7];
        #pragma unroll
        for (int b = 6; b >= 0; --b) vb = (h[b] == hm) ? v0[b] : vb;  // first-argmax
        va[a] = vb;
    }
}

// c2 = va[0] + log2(S), S = sum_a exp2(Dp[a]-va[a]) * R[a], Dp[0]=0 implied.
__device__ __forceinline__ float token_core(const float f2[8], const float va[8],
                                            const float Dp[7],
                                            const float* __restrict__ et) {
    float ef[8];
    #pragma unroll
    for (int b = 0; b < 8; ++b) ef[b] = __builtin_amdgcn_exp2f(f2[b]);
    float R[8] = {0, 0, 0, 0, 0, 0, 0, 0};
    #pragma unroll
    for (int b = 0; b < 8; ++b) {
        const float efb = ef[b];
        #pragma unroll
        for (int a = 0; a < 8; ++a) R[a] = fmaf(efb, et[b * 8 + a], R[a]);
    }
    float S = __builtin_amdgcn_exp2f(-va[0]) * R[0];
    #pragma unroll
    for (int a = 1; a < 8; ++a)
        S += __builtin_amdgcn_exp2f(Dp[a - 1] - va[a]) * R[a];
    return va[0] + __builtin_amdgcn_logf(S);
}

__device__ __forceinline__ float emit_sel(const float f2[8], int tag) {
    float e = f2[0];
    #pragma unroll
    for (int b = 1; b < 6; ++b) e = (tag == b) ? f2[b] : e;
    return e;
}

// 256 threads; thread owns tokens (2*local, 2*local+1); block = 512 tokens.
__global__ __launch_bounds__(256) void crf_main_kernel(
    const float* __restrict__ wf,      // [T][8]
    const int*   __restrict__ tc,      // [T]
    const float* __restrict__ t2,      // T*log2e [64], t2[next*8+prev]
    const float* __restrict__ et,      // exp(T) [64]
    float* __restrict__ partials)      // [gridDim.x]
{
    const int local = threadIdx.x;
    const int tokA  = blockIdx.x * 512 + 2 * local;
    const int tA    = (2 * local) & 127;          // even position in sequence
    const bool activeA = (tA != 0);               // A==START iff tA==0
    const bool activeB = (tA != 126);             // B==STOP  iff tA==126

    __shared__ float Dlds[7][256];
    __shared__ int   tagLds[256];
    __shared__ float red[4];

    // ---- loads: 64B features + 8B tags per thread (fully coalesced) ----
    const float4* wf4 = reinterpret_cast<const float4*>(wf) + (size_t)tokA * 2;
    float4 xa = wf4[0], ya = wf4[1], xb = wf4[2], yb = wf4[3];
    float f2A[8] = {xa.x*L2E, xa.y*L2E, xa.z*L2E, xa.w*L2E,
                    ya.x*L2E, ya.y*L2E, ya.z*L2E, ya.w*L2E};
    float f2B[8] = {xb.x*L2E, xb.y*L2E, xb.z*L2E, xb.w*L2E,
                    yb.x*L2E, yb.y*L2E, yb.z*L2E, yb.w*L2E};
    const int2 tg = *reinterpret_cast<const int2*>(tc + tokA);
    const int tagA = tg.x, tagB = tg.y;

    float vaA[8], vaB[8];
    compute_va(f2A, t2, vaA);
    compute_va(f2B, t2, vaB);

    // publish B's D (read by next thread's A) and tagA (read by prev thread's B)
    #pragma unroll
    for (int a = 1; a < 8; ++a) Dlds[a - 1][local] = vaB[a] - vaB[0];
    tagLds[local] = tagA;
    __syncthreads();

    float c = 0.0f;

    // ---- token A: Dp from LDS (prev thread's B) ----
    {
        const int pidx = (local == 0) ? 0 : local - 1;   // bounds clamp only
        float Dp[7];
        #pragma unroll
        for (int a = 0; a < 7; ++a) Dp[a] = Dlds[a][pidx];

        float cA = token_core(f2A, vaA, Dp, et);

        if (tA == 126) {  // final STOP logsumexp over D(126), base-2
            float D[8];
            D[0] = 0.0f;
            #pragma unroll
            for (int a = 1; a < 8; ++a) D[a] = vaA[a] - vaA[0];
            float m = fmaxf(fmaxf(fmaxf(fmaxf(D[0], D[1]), D[2]),
                                  fmaxf(fmaxf(D[3], D[4]), D[5])),
                            fmaxf(D[6], D[7]));
            float s2 = 0.0f;
            #pragma unroll
            for (int a = 0; a < 8; ++a) s2 += __builtin_amdgcn_exp2f(D[a] - m);
            cA += m + __builtin_amdgcn_logf(s2);
        }
        // truth path: emit + T[tag_next, tag]; trans term cancels at t==126
        float tr = (tA != 126) ? t2[tagB * 8 + tagA] : 0.0f;
        cA -= emit_sel(f2A, tagA) + tr;
        c += activeA ? cA : 0.0f;
    }

    // ---- token B: Dp from token A's registers (0 if A is START) ----
    {
        float Dp[7];
        #pragma unroll
        for (int a = 0; a < 7; ++a)
            Dp[a] = activeA ? (vaA[a + 1] - vaA[0]) : 0.0f;

        float cB = token_core(f2B, vaB, Dp, et);

        const int nidx = (local == 255) ? 255 : local + 1;
        const int tagN = tagLds[nidx];                 // tag of token B+1
        cB -= emit_sel(f2B, tagB) + t2[tagN * 8 + tagB];  // B never at t==126
        c += activeB ? cB : 0.0f;
    }

    // ---- block reduction ----
    #pragma unroll
    for (int off = 32; off >= 1; off >>= 1) c += __shfl_xor(c, off, 64);
    if ((local & 63) == 0) red[local >> 6] = c;
    __syncthreads();
    if (local == 0) partials[blockIdx.x] = red[0] + red[1] + red[2] + red[3];
}

// 512 threads; n == 2048 -> one float4 per thread. Final scale by ln2.
__global__ __launch_bounds__(512) void reduce_kernel(
    const float* __restrict__ partials, int n, float* __restrict__ out)
{
    __shared__ float red[8];
    float s = 0.0f;
    for (int i = threadIdx.x; i * 4 < n; i += 512) {
        float4 p = reinterpret_cast<const float4*>(partials)[i];
        s += (p.x + p.y) + (p.z + p.w);
    }
    #pragma unroll
    for (int off = 32; off >= 1; off >>= 1) s += __shfl_xor(s, off, 64);
    if ((threadIdx.x & 63) == 0) red[threadIdx.x >> 6] = s;
    __syncthreads();
    if (threadIdx.x == 0) {
        float tot = 0.0f;
        #pragma unroll
        for (int w = 0; w < 8; ++w) tot += red[w];
        out[0] = tot * LN2;
    }
}

extern "C" void kernel_launch(void* const* d_in, const int* in_sizes, int n_in,
                              void* d_out, int out_size, void* d_ws, size_t ws_size,
                              hipStream_t stream) {
    const float* wf    = (const float*)d_in[0];
    const int*   tc    = (const int*)d_in[2];
    const float* trans = (const float*)d_in[3];

    const int T = in_sizes[1];          // 8192 * 128 = 1048576 tokens
    const int nblocks = T / 512;        // 2048

    float* et       = (float*)d_ws;                      // 64 floats
    float* t2       = (float*)((char*)d_ws + 256);       // 64 floats
    float* partials = (float*)((char*)d_ws + 1024);      // nblocks floats

    prep_kernel<<<1, 64, 0, stream>>>(trans, et, t2);
    crf_main_kernel<<<nblocks, 256, 0, stream>>>(wf, tc, t2, et, partials);
    reduce_kernel<<<1, 512, 0, stream>>>(partials, nblocks, (float*)d_out);
}

// Round 5
// 23.614 us; speedup vs baseline: 1.5803x; 1.5803x over previous
//
#include <hip/hip_runtime.h>

// CRF forward (buggy-LSE reference) telescoped into per-token parallel form.
// R5: R3's proven structure (1 token/thread, 4096 blocks, 3 dispatches)
// + base-2 math only (isolated variable). exp->v_exp_f32, log->v_log_f32,
// v0/h rows as single v_fma; one xln2 at the end of the reduce.
//
// ws layout: [0] 64f et=exp(T) ; [256B] 64f t2=T*log2e ; [1024B] partials[4096].

#define L2E 1.44269504088896340736f
#define LN2 0.69314718055994530942f

__global__ void prep_kernel(const float* __restrict__ trans,
                            float* __restrict__ et, float* __restrict__ t2) {
    int i = threadIdx.x;   // 64 threads
    float v = trans[i];
    et[i] = __expf(v);     // natural-e: multiplies exp(feat) values
    t2[i] = v * L2E;       // base-2 domain for all additive terms
}

// 256 threads = 2 sequences of 128 tokens. Thread <-> token.
__global__ __launch_bounds__(256) void crf_main_kernel(
    const float* __restrict__ wf,      // [T][8]
    const int*   __restrict__ tc,      // [T]
    const float* __restrict__ t2,      // T*log2e [64], t2[next*8+prev]
    const float* __restrict__ et,      // exp(T) [64]
    float* __restrict__ partials)      // [gridDim.x]
{
    const int local = threadIdx.x;
    const int tok   = blockIdx.x * 256 + local;   // global token index
    const int t     = local & 127;                // position within sequence
    const bool active = (t >= 1) && (t <= 126);   // interior tokens only

    __shared__ float Dlds[7][256];
    __shared__ int   tagLds[256];
    __shared__ float red[4];

    // unconditional coalesced loads (every tok is a valid address)
    const float4* wf4 = reinterpret_cast<const float4*>(wf) + (size_t)tok * 2;
    float4 x = wf4[0];
    float4 y = wf4[1];
    const float f[8] = {x.x, x.y, x.z, x.w, y.x, y.y, y.z, y.w};
    const int tag = tc[tok];

    float va[8];   // per row a: payload-at-argmax (base-2 units)
    if (active) {
        // v0[b] = (feat[b] + T[b,0]) * log2e  as one fma
        float v0[8];
        #pragma unroll
        for (int b = 0; b < 8; ++b) v0[b] = fmaf(f[b], L2E, t2[b * 8]);

        // row 0: keys == payloads -> payload at argmax is the max
        va[0] = fmaxf(fmaxf(fmaxf(fmaxf(v0[0], v0[1]), v0[2]),
                            fmaxf(fmaxf(v0[3], v0[4]), v0[5])),
                      fmaxf(v0[6], v0[7]));

        #pragma unroll
        for (int a = 1; a < 8; ++a) {
            float h[8];
            #pragma unroll
            for (int b = 0; b < 8; ++b) h[b] = fmaf(f[b], L2E, t2[b * 8 + a]);
            float hm = fmaxf(fmaxf(fmaxf(fmaxf(h[0], h[1]), h[2]),
                                   fmaxf(fmaxf(h[3], h[4]), h[5])),
                             fmaxf(h[6], h[7]));
            float vb = v0[7];
            #pragma unroll
            for (int b = 6; b >= 0; --b) vb = (h[b] == hm) ? v0[b] : vb;  // first-argmax
            va[a] = vb;
        }
    }

    // publish D_a = va[a] - va[0] for the next token; START (t==0) publishes 0
    if (t == 0) {
        #pragma unroll
        for (int a = 1; a < 8; ++a) Dlds[a - 1][local] = 0.0f;
    } else if (active) {
        #pragma unroll
        for (int a = 1; a < 8; ++a) Dlds[a - 1][local] = va[a] - va[0];
    }
    tagLds[local] = tag;
    __syncthreads();

    float c = 0.0f;
    if (active) {
        float Dp[7];
        #pragma unroll
        for (int a = 0; a < 7; ++a) Dp[a] = Dlds[a][local - 1];

        float f2[8], ef[8];
        #pragma unroll
        for (int b = 0; b < 8; ++b) {
            f2[b] = f[b] * L2E;
            ef[b] = __builtin_amdgcn_exp2f(f2[b]);   // = exp(feat[b])
        }

        // R[a] = sum_b exp(feat[b]) * exp(T[b,a])   (et uniform -> scalar loads)
        float R[8] = {0, 0, 0, 0, 0, 0, 0, 0};
        #pragma unroll
        for (int b = 0; b < 8; ++b) {
            const float efb = ef[b];
            #pragma unroll
            for (int a = 0; a < 8; ++a) R[a] = fmaf(efb, et[b * 8 + a], R[a]);
        }

        // S = sum_a exp2(Dp_a - va_a) * R[a];  Dp_0 = 0 implied
        float S = __builtin_amdgcn_exp2f(-va[0]) * R[0];
        #pragma unroll
        for (int a = 1; a < 8; ++a)
            S += __builtin_amdgcn_exp2f(Dp[a - 1] - va[a]) * R[a];

        c = va[0] + __builtin_amdgcn_logf(S);   // log2; scaled by ln2 at the end

        // last interior token: exact logsumexp over D(126) (final STOP lse), base-2
        if (t == 126) {
            float D[8];
            D[0] = 0.0f;
            #pragma unroll
            for (int a = 1; a < 8; ++a) D[a] = va[a] - va[0];
            float m = fmaxf(fmaxf(fmaxf(fmaxf(D[0], D[1]), D[2]),
                                  fmaxf(fmaxf(D[3], D[4]), D[5])),
                            fmaxf(D[6], D[7]));
            float s2 = 0.0f;
            #pragma unroll
            for (int a = 0; a < 8; ++a) s2 += __builtin_amdgcn_exp2f(D[a] - m);
            c += m + __builtin_amdgcn_logf(s2);
        }

        // truth path (subtracted), base-2 units. tag in [0,6) for interior
        // tokens -> select emit from registers. At t==126 the T[7,tag] term
        // cancels with the STOP step's -T[7,tag_prev].
        float emit = f2[0];
        #pragma unroll
        for (int b = 1; b < 6; ++b) emit = (tag == b) ? f2[b] : emit;
        float tr = 0.0f;
        if (t < 126) {
            int tagn = tagLds[local + 1];
            tr = t2[tagn * 8 + tag];
        }
        c -= emit + tr;
    }

    // block reduction of contributions
    #pragma unroll
    for (int off = 32; off >= 1; off >>= 1) c += __shfl_xor(c, off, 64);
    if ((local & 63) == 0) red[local >> 6] = c;
    __syncthreads();
    if (local == 0) partials[blockIdx.x] = red[0] + red[1] + red[2] + red[3];
}

// 1024 threads; n == 4096 -> one float4 per thread. Final scale by ln2.
__global__ __launch_bounds__(1024) void reduce_kernel(
    const float* __restrict__ partials, int n, float* __restrict__ out)
{
    __shared__ float red[16];
    float s = 0.0f;
    for (int i = threadIdx.x; i * 4 < n; i += 1024) {
        float4 p = reinterpret_cast<const float4*>(partials)[i];
        s += (p.x + p.y) + (p.z + p.w);
    }
    #pragma unroll
    for (int off = 32; off >= 1; off >>= 1) s += __shfl_xor(s, off, 64);
    if ((threadIdx.x & 63) == 0) red[threadIdx.x >> 6] = s;
    __syncthreads();
    if (threadIdx.x == 0) {
        float tot = 0.0f;
        #pragma unroll
        for (int w = 0; w < 16; ++w) tot += red[w];
        out[0] = tot * LN2;
    }
}

extern "C" void kernel_launch(void* const* d_in, const int* in_sizes, int n_in,
                              void* d_out, int out_size, void* d_ws, size_t ws_size,
                              hipStream_t stream) {
    const float* wf    = (const float*)d_in[0];
    const int*   tc    = (const int*)d_in[2];
    const float* trans = (const float*)d_in[3];

    const int T = in_sizes[1];          // 8192 * 128 = 1048576 tokens
    const int nblocks = T / 256;        // 4096

    float* et       = (float*)d_ws;                      // 64 floats
    float* t2       = (float*)((char*)d_ws + 256);       // 64 floats
    float* partials = (float*)((char*)d_ws + 1024);      // nblocks floats

    prep_kernel<<<1, 64, 0, stream>>>(trans, et, t2);
    crf_main_kernel<<<nblocks, 256, 0, stream>>>(wf, tc, t2, et, partials);
    reduce_kernel<<<1, 1024, 0, stream>>>(partials, nblocks, (float*)d_out);
}

// Round 6
// 18.887 us; speedup vs baseline: 1.9759x; 1.2503x over previous
//
#include <hip/hip_runtime.h>

// CRF forward (buggy-LSE reference) telescoped into per-token parallel form.
// R6: fuse prep into main (tables built per-block in LDS) -> 2 dispatches.
// Structure otherwise identical to R5 (1 token/thread, 4096x256, base-2 math).
//
// ws layout: [0] partials [4096] floats.

#define L2E 1.44269504088896340736f
#define LN2 0.69314718055994530942f

// 256 threads = 2 sequences of 128 tokens. Thread <-> token.
__global__ __launch_bounds__(256) void crf_main_kernel(
    const float* __restrict__ wf,      // [T][8]
    const int*   __restrict__ tc,      // [T]
    const float* __restrict__ trans,   // [8][8] trans[next*8+prev]
    float* __restrict__ partials)      // [gridDim.x]
{
    const int local = threadIdx.x;
    const int tok   = blockIdx.x * 256 + local;   // global token index
    const int t     = local & 127;                // position within sequence
    const bool active = (t >= 1) && (t <= 126);   // interior tokens only

    // t2t[a*8+b] = trans[b*8+a] * log2e  (transposed -> row-contiguous per a)
    // et[b*8+a]  = exp(trans[b*8+a])     (row-contiguous per b)
    __shared__ float t2t[64];
    __shared__ float et[64];
    __shared__ float Dlds[7][256];
    __shared__ int   tagLds[256];
    __shared__ float red[4];

    // ---- phase 0: build tables (threads 0..63) ----
    if (local < 64) {
        const int b = local >> 3, a = local & 7;   // local = b*8+a
        float v = trans[local];                    // T[next=b, prev=a]
        float v2 = v * L2E;
        t2t[a * 8 + b] = v2;
        et[local] = __builtin_amdgcn_exp2f(v2);    // exp(T[b,a])
    }

    // unconditional coalesced loads (every tok is a valid address)
    const float4* wf4 = reinterpret_cast<const float4*>(wf) + (size_t)tok * 2;
    float4 x = wf4[0];
    float4 y = wf4[1];
    const float f[8] = {x.x, x.y, x.z, x.w, y.x, y.y, y.z, y.w};
    const int tag = tc[tok];

    __syncthreads();   // tables ready

    const float4* t2t4 = reinterpret_cast<const float4*>(t2t);
    const float4* et4  = reinterpret_cast<const float4*>(et);

    float va[8];   // per row a: payload-at-argmax (base-2 units)
    if (active) {
        // v0[b] = (feat[b] + T[b,0]) * log2e  as one fma ; row a=0 of t2t
        float v0[8];
        {
            float4 ta = t2t4[0], tb = t2t4[1];
            const float tr0[8] = {ta.x, ta.y, ta.z, ta.w, tb.x, tb.y, tb.z, tb.w};
            #pragma unroll
            for (int b = 0; b < 8; ++b) v0[b] = fmaf(f[b], L2E, tr0[b]);
        }

        // row 0: keys == payloads -> payload at argmax is the max
        va[0] = fmaxf(fmaxf(fmaxf(fmaxf(v0[0], v0[1]), v0[2]),
                            fmaxf(fmaxf(v0[3], v0[4]), v0[5])),
                      fmaxf(v0[6], v0[7]));

        #pragma unroll
        for (int a = 1; a < 8; ++a) {
            float4 ta = t2t4[a * 2], tb = t2t4[a * 2 + 1];
            const float tra[8] = {ta.x, ta.y, ta.z, ta.w, tb.x, tb.y, tb.z, tb.w};
            float h[8];
            #pragma unroll
            for (int b = 0; b < 8; ++b) h[b] = fmaf(f[b], L2E, tra[b]);
            float hm = fmaxf(fmaxf(fmaxf(fmaxf(h[0], h[1]), h[2]),
                                   fmaxf(fmaxf(h[3], h[4]), h[5])),
                             fmaxf(h[6], h[7]));
            float vb = v0[7];
            #pragma unroll
            for (int b = 6; b >= 0; --b) vb = (h[b] == hm) ? v0[b] : vb;  // first-argmax
            va[a] = vb;
        }
    }

    // publish D_a = va[a] - va[0] for the next token; START (t==0) publishes 0
    if (t == 0) {
        #pragma unroll
        for (int a = 1; a < 8; ++a) Dlds[a - 1][local] = 0.0f;
    } else if (active) {
        #pragma unroll
        for (int a = 1; a < 8; ++a) Dlds[a - 1][local] = va[a] - va[0];
    }
    tagLds[local] = tag;
    __syncthreads();

    float c = 0.0f;
    if (active) {
        float Dp[7];
        #pragma unroll
        for (int a = 0; a < 7; ++a) Dp[a] = Dlds[a][local - 1];

        float f2[8], ef[8];
        #pragma unroll
        for (int b = 0; b < 8; ++b) {
            f2[b] = f[b] * L2E;
            ef[b] = __builtin_amdgcn_exp2f(f2[b]);   // = exp(feat[b])
        }

        // R[a] = sum_b exp(feat[b]) * exp(T[b,a])
        float R[8] = {0, 0, 0, 0, 0, 0, 0, 0};
        #pragma unroll
        for (int b = 0; b < 8; ++b) {
            float4 ea = et4[b * 2], eb = et4[b * 2 + 1];
            const float erow[8] = {ea.x, ea.y, ea.z, ea.w, eb.x, eb.y, eb.z, eb.w};
            const float efb = ef[b];
            #pragma unroll
            for (int a = 0; a < 8; ++a) R[a] = fmaf(efb, erow[a], R[a]);
        }

        // S = sum_a exp2(Dp_a - va_a) * R[a];  Dp_0 = 0 implied
        float S = __builtin_amdgcn_exp2f(-va[0]) * R[0];
        #pragma unroll
        for (int a = 1; a < 8; ++a)
            S += __builtin_amdgcn_exp2f(Dp[a - 1] - va[a]) * R[a];

        c = va[0] + __builtin_amdgcn_logf(S);   // log2; scaled by ln2 at the end

        // last interior token: exact logsumexp over D(126) (final STOP lse), base-2
        if (t == 126) {
            float D[8];
            D[0] = 0.0f;
            #pragma unroll
            for (int a = 1; a < 8; ++a) D[a] = va[a] - va[0];
            float m = fmaxf(fmaxf(fmaxf(fmaxf(D[0], D[1]), D[2]),
                                  fmaxf(fmaxf(D[3], D[4]), D[5])),
                            fmaxf(D[6], D[7]));
            float s2 = 0.0f;
            #pragma unroll
            for (int a = 0; a < 8; ++a) s2 += __builtin_amdgcn_exp2f(D[a] - m);
            c += m + __builtin_amdgcn_logf(s2);
        }

        // truth path (subtracted), base-2 units. tag in [0,6) for interior
        // tokens -> select emit from registers. At t==126 the T[7,tag] term
        // cancels with the STOP step's -T[7,tag_prev].
        float emit = f2[0];
        #pragma unroll
        for (int b = 1; b < 6; ++b) emit = (tag == b) ? f2[b] : emit;
        float tr = 0.0f;
        if (t < 126) {
            int tagn = tagLds[local + 1];
            tr = t2t[tag * 8 + tagn];     // trans[tagn*8+tag] * log2e
        }
        c -= emit + tr;
    }

    // block reduction of contributions
    #pragma unroll
    for (int off = 32; off >= 1; off >>= 1) c += __shfl_xor(c, off, 64);
    if ((local & 63) == 0) red[local >> 6] = c;
    __syncthreads();
    if (local == 0) partials[blockIdx.x] = red[0] + red[1] + red[2] + red[3];
}

// 1024 threads; n == 4096 -> one float4 per thread. Final scale by ln2.
__global__ __launch_bounds__(1024) void reduce_kernel(
    const float* __restrict__ partials, int n, float* __restrict__ out)
{
    __shared__ float red[16];
    float s = 0.0f;
    for (int i = threadIdx.x; i * 4 < n; i += 1024) {
        float4 p = reinterpret_cast<const float4*>(partials)[i];
        s += (p.x + p.y) + (p.z + p.w);
    }
    #pragma unroll
    for (int off = 32; off >= 1; off >>= 1) s += __shfl_xor(s, off, 64);
    if ((threadIdx.x & 63) == 0) red[threadIdx.x >> 6] = s;
    __syncthreads();
    if (threadIdx.x == 0) {
        float tot = 0.0f;
        #pragma unroll
        for (int w = 0; w < 16; ++w) tot += red[w];
        out[0] = tot * LN2;
    }
}

extern "C" void kernel_launch(void* const* d_in, const int* in_sizes, int n_in,
                              void* d_out, int out_size, void* d_ws, size_t ws_size,
                              hipStream_t stream) {
    const float* wf    = (const float*)d_in[0];
    const int*   tc    = (const int*)d_in[2];
    const float* trans = (const float*)d_in[3];

    const int T = in_sizes[1];          // 8192 * 128 = 1048576 tokens
    const int nblocks = T / 256;        // 4096

    float* partials = (float*)d_ws;     // nblocks floats

    crf_main_kernel<<<nblocks, 256, 0, stream>>>(wf, tc, trans, partials);
    reduce_kernel<<<1, 1024, 0, stream>>>(partials, nblocks, (float*)d_out);
}